// Round 4
// baseline (723.373 us; speedup 1.0000x reference)
//
#include <hip/hip_runtime.h>
#include <hip/hip_bf16.h>

#define N_NODES 100000
#define N_EDGES 3200000
#define N_GRAPHS 4096
#define N_REL 5
#define N_BASES 4
#define HID 32
#define SEG (N_NODES*N_REL)

#define NBUCK 196        // ceil(100000/512) buckets of 512 dst nodes
#define BCAP  20480      // per-bucket capacity (mean 16327, huge margin)
#define NKEY  2560       // 512 nodes * 5 rels per bucket

// ---------------- CSR pass 1: partition edges into dst-range buckets ----------------
static __global__ __launch_bounds__(256) void k_part(const int* __restrict__ ei,
                                                     const int* __restrict__ et,
                                                     int* __restrict__ gcur,
                                                     unsigned long long* __restrict__ part) {
    __shared__ int hcnt[NBUCK];
    __shared__ int lbase[NBUCK];
    int t = threadIdx.x;
    if (t < NBUCK) hcnt[t] = 0;
    __syncthreads();
    int e0 = blockIdx.x * 2048;
    int src[8], bkt[8], lkey[8];
#pragma unroll
    for (int j = 0; j < 8; j++) {
        int e = e0 + j * 256 + t;
        if (e < N_EDGES) {
            int s = ei[e];
            int d = ei[N_EDGES + e];
            int r = et[e];
            src[j] = s; bkt[j] = d >> 9; lkey[j] = ((d & 511) * 5) + r;
            atomicAdd(&hcnt[bkt[j]], 1);
        } else bkt[j] = -1;
    }
    __syncthreads();
    if (t < NBUCK) lbase[t] = atomicAdd(&gcur[t], hcnt[t]);
    __syncthreads();
    if (t < NBUCK) hcnt[t] = 0;   // reuse as intra-block cursor
    __syncthreads();
#pragma unroll
    for (int j = 0; j < 8; j++) {
        if (bkt[j] >= 0) {
            int rank = atomicAdd(&hcnt[bkt[j]], 1);
            int p = lbase[bkt[j]] + rank;
            if (p < BCAP)
                part[(size_t)bkt[j] * BCAP + p] =
                    ((unsigned long long)(unsigned)lkey[j] << 32) | (unsigned)src[j];
        }
    }
}

// ---------------- CSR pass 2: per-bucket counting sort fully in LDS ----------------
static __global__ __launch_bounds__(512) void k_bsort(const unsigned long long* __restrict__ part,
                                                      const int* __restrict__ gcur,
                                                      int* __restrict__ offs,
                                                      int* __restrict__ cnt,
                                                      int* __restrict__ srcs) {
    __shared__ int lhist[NKEY];
    __shared__ int lscan[NKEY];
    __shared__ int lsrc[BCAP];
    __shared__ int sscan[512];
    __shared__ int warpsum[8];
    __shared__ int sstart;
    int b = blockIdx.x;
    int t = threadIdx.x;

    int psum = (t < b) ? gcur[t] : 0;
#pragma unroll
    for (int off = 32; off > 0; off >>= 1) psum += __shfl_down(psum, off);
    if ((t & 63) == 0) warpsum[t >> 6] = psum;
    __syncthreads();
    if (t == 0) { int s = 0; for (int w = 0; w < 8; w++) s += warpsum[w]; sstart = s; }
    int n = gcur[b]; if (n > BCAP) n = BCAP;
    const unsigned long long* reg = part + (size_t)b * BCAP;

#pragma unroll
    for (int k = t; k < NKEY; k += 512) lhist[k] = 0;
    __syncthreads();
    for (int i = t; i < n; i += 512) {
        unsigned long long u = reg[i];
        atomicAdd(&lhist[(int)(u >> 32)], 1);
    }
    __syncthreads();

    int loc[5]; int s5 = 0;
#pragma unroll
    for (int j = 0; j < 5; j++) { loc[j] = s5; s5 += lhist[t * 5 + j]; }
    sscan[t] = s5;
    __syncthreads();
    for (int off = 1; off < 512; off <<= 1) {
        int x = (t >= off) ? sscan[t - off] : 0;
        __syncthreads();
        sscan[t] += x;
        __syncthreads();
    }
    int excl = sscan[t] - s5;
#pragma unroll
    for (int j = 0; j < 5; j++) lscan[t * 5 + j] = excl + loc[j];
    __syncthreads();

    int base = sstart;
#pragma unroll
    for (int j = 0; j < 5; j++) {
        int k = t * 5 + j;
        int segid = b * NKEY + k;
        if (segid < SEG) {
            cnt[segid]  = lhist[k];
            offs[segid] = base + lscan[k];
        }
    }
    __syncthreads();
#pragma unroll
    for (int k = t; k < NKEY; k += 512) lhist[k] = 0;
    __syncthreads();
    for (int i = t; i < n; i += 512) {
        unsigned long long u = reg[i];
        int k = (int)(u >> 32);
        int pos = lscan[k] + atomicAdd(&lhist[k], 1);
        lsrc[pos] = (int)(u & 0xffffffffULL);
    }
    __syncthreads();
    for (int i = t; i < n; i += 512) srcs[base + i] = lsrc[i];
}

// ---------------- layer-0 input padding ----------------
static __global__ __launch_bounds__(256) void k_pad(const float* __restrict__ x,
                                                    float* __restrict__ x32) {
    int tid = blockIdx.x * 256 + threadIdx.x;
    int n = tid >> 5, i = tid & 31;
    x32[tid] = (i < 4) ? x[(n << 2) + i] : 0.f;
}

// ---------------- per-layer weight prep ----------------
static __global__ __launch_bounds__(256) void k_wprep(const float* __restrict__ basis,
                                                      const float* __restrict__ root,
                                                      int in_c, float* __restrict__ Wp) {
    int idx = blockIdx.x * 256 + threadIdx.x;
    int kc = idx >> 7, rem = idx & 127;
    int o = rem >> 2, j = rem & 3;
    int k = kc * 4 + j;
    float v;
    if (k < 128) {
        int b = k >> 5, ii = k & 31;
        v = (ii < in_c) ? basis[(b * in_c + ii) * HID + o] : 0.f;
    } else {
        int ii = k - 128;
        v = (ii < in_c) ? root[ii * HID + o] : 0.f;
    }
    Wp[kc * 128 + o * 4 + j] = v;
}

static __global__ __launch_bounds__(256) void k_wprep4(
    const float* __restrict__ ba0, const float* __restrict__ ro0,
    const float* __restrict__ ba1, const float* __restrict__ ro1,
    const float* __restrict__ ba2, const float* __restrict__ ro2,
    const float* __restrict__ ba3, const float* __restrict__ ro3,
    float* __restrict__ Wp) {
    int l = blockIdx.y;
    const float* basis = (l == 0) ? ba0 : (l == 1) ? ba1 : (l == 2) ? ba2 : ba3;
    const float* root  = (l == 0) ? ro0 : (l == 1) ? ro1 : (l == 2) ? ro2 : ro3;
    int in_c = (l == 0) ? 4 : HID;
    int idx = blockIdx.x * 256 + threadIdx.x;
    int kc = idx >> 7, rem = idx & 127;
    int o = rem >> 2, j = rem & 3;
    int k = kc * 4 + j;
    float v;
    if (k < 128) {
        int b = k >> 5, ii = k & 31;
        v = (ii < in_c) ? basis[(b * in_c + ii) * HID + o] : 0.f;
    } else {
        int ii = k - 128;
        v = (ii < in_c) ? root[ii * HID + o] : 0.f;
    }
    Wp[l * 5120 + kc * 128 + o * 4 + j] = v;
}

// ---------------- fused RGCN layer ----------------
// DPP butterfly over the 8 edge-groups (lanes l, l^1, l^2, l^4 within each
// 8-lane block): quad_perm xor1, quad_perm xor2, row_half_mirror. Pure VALU.
static __device__ __forceinline__ float red8(float v) {
    v += __int_as_float(__builtin_amdgcn_mov_dpp(__float_as_int(v), 0xB1, 0xf, 0xf, true));  // xor 1
    v += __int_as_float(__builtin_amdgcn_mov_dpp(__float_as_int(v), 0x4E, 0xf, 0xf, true));  // xor 2
    v += __int_as_float(__builtin_amdgcn_mov_dpp(__float_as_int(v), 0x141, 0xf, 0xf, true)); // half-mirror
    return v;
}
#define FMA4(A, s, V) { A.x += (s)*(V).x; A.y += (s)*(V).y; A.z += (s)*(V).z; A.w += (s)*(V).w; }

// Wave = 1 node (4 nodes sequentially). lane = (g = edge slot 0..7, q = dim
// quarter 0..7). Relation runs contiguous in srcs: inner loop is bpermute-src
// + float4 gather + 4 masked adds; comp-weight fold hoisted per run (SGPR
// weights); DPP reduce across groups; phase 2 unchanged.
template <int STRIDE>
static __global__ __launch_bounds__(256, 4) void k_layer(
    const float* __restrict__ hin, const int* __restrict__ offs,
    const int* __restrict__ cnt, const int* __restrict__ srcs,
    const float* __restrict__ comp, const float* __restrict__ Wp,
    const float* __restrict__ bias, float* __restrict__ hall, int hall_off) {
    __shared__ __align__(16) float sAgg[16][160];   // 10 KB
    int t = threadIdx.x;
    int wave = t >> 6, lane = t & 63;
    int g = lane & 7, q = lane >> 3;
    const float* hq = hin + q * 4;

    // comp[r][b] -> uniform loads (SGPR-resident)
    float4 cw0 = *(const float4*)(comp + 0);
    float4 cw1 = *(const float4*)(comp + 4);
    float4 cw2 = *(const float4*)(comp + 8);
    float4 cw3 = *(const float4*)(comp + 12);
    float4 cw4 = *(const float4*)(comp + 16);

    int nb = blockIdx.x * 16 + wave * 4;            // N_NODES = 6250*16
    int Bv[4], cv[4][5];
#pragma unroll
    for (int nn = 0; nn < 4; nn++) {
        int s5 = (nb + nn) * N_REL;
        Bv[nn] = offs[s5];
#pragma unroll
        for (int r = 0; r < 5; r++) cv[nn][r] = cnt[s5 + r];
    }

    for (int nn = 0; nn < 4; nn++) {
        int n = nb + nn;
        int B = __builtin_amdgcn_readfirstlane(Bv[nn]);
        int c0 = __builtin_amdgcn_readfirstlane(cv[nn][0]);
        int c1 = __builtin_amdgcn_readfirstlane(cv[nn][1]);
        int c2 = __builtin_amdgcn_readfirstlane(cv[nn][2]);
        int c3 = __builtin_amdgcn_readfirstlane(cv[nn][3]);
        int c4 = __builtin_amdgcn_readfirstlane(cv[nn][4]);
        int c[5] = {c0, c1, c2, c3, c4};
        int deg = c0 + c1 + c2 + c3 + c4;
        int dl = (deg > 0) ? deg - 1 : 0;
        int sv0 = srcs[B + min(lane, dl)];          // prefetch up to 128 srcs
        int sv1 = srcs[B + min(lane + 64, dl)];
        float4 self4 = *(const float4*)(hq + n * STRIDE);
        float4 A0 = {0,0,0,0}, A1 = {0,0,0,0}, A2 = {0,0,0,0}, A3 = {0,0,0,0};
        int rbl = 0;
#pragma unroll
        for (int r = 0; r < 5; r++) {
            int cr = c[r];
            if (cr > 0) {
                float4 S = {0,0,0,0};
                int rend1 = rbl + cr - 1;
                for (int it = 0; it < cr; it += 8) {
                    int it8 = rbl + it;
                    int lidx = min(it8 + g, rend1);
                    int src;
                    if (it8 + 8 <= 128) {                    // scalar branch
                        int a = (lidx & 63) << 2;
                        int p0 = __builtin_amdgcn_ds_bpermute(a, sv0);
                        int p1 = __builtin_amdgcn_ds_bpermute(a, sv1);
                        src = (lidx < 64) ? p0 : p1;
                    } else {
                        src = srcs[B + lidx];                // deg > 128 (rare)
                    }
                    float mk = (g < cr - it) ? 1.0f : 0.0f;
                    float4 h = *(const float4*)(hq + src * STRIDE);
                    S.x += mk * h.x; S.y += mk * h.y;
                    S.z += mk * h.z; S.w += mk * h.w;
                }
                float ic = __builtin_amdgcn_rcpf((float)cr);
                float4 Sc; Sc.x = S.x * ic; Sc.y = S.y * ic;
                Sc.z = S.z * ic; Sc.w = S.w * ic;
                float4 cw = (r == 0) ? cw0 : (r == 1) ? cw1 : (r == 2) ? cw2
                          : (r == 3) ? cw3 : cw4;
                FMA4(A0, cw.x, Sc); FMA4(A1, cw.y, Sc);
                FMA4(A2, cw.z, Sc); FMA4(A3, cw.w, Sc);
            }
            rbl += cr;
        }
        // reduce over the 8 edge-groups (pure DPP, all lanes end with totals)
        A0.x = red8(A0.x); A0.y = red8(A0.y); A0.z = red8(A0.z); A0.w = red8(A0.w);
        A1.x = red8(A1.x); A1.y = red8(A1.y); A1.z = red8(A1.z); A1.w = red8(A1.w);
        A2.x = red8(A2.x); A2.y = red8(A2.y); A2.z = red8(A2.z); A2.w = red8(A2.w);
        A3.x = red8(A3.x); A3.y = red8(A3.y); A3.z = red8(A3.z); A3.w = red8(A3.w);
        int nl = wave * 4 + nn;
        float4* sv4 = (float4*)&sAgg[nl][0];
        if (g == 0) { sv4[q] = A0; sv4[8 + q] = A1; sv4[16 + q] = A2; sv4[24 + q] = A3; }
        if (g == 1) { sv4[32 + q] = self4; }
    }
    __syncthreads();

    // phase 2: K=160 matvec, W float4 from global (L1-resident 20 KB)
    int half = (t >> 5) & 1, i = t & 31;
    int mynode = wave * 4 + half * 2;
    const float4* wv = (const float4*)Wp;
    const float4* aA = (const float4*)&sAgg[mynode][0];
    const float4* aB = (const float4*)&sAgg[mynode + 1][0];
    float acc0 = 0.f, acc1 = 0.f;
#pragma unroll 8
    for (int kc = 0; kc < 40; kc++) {
        float4 w4 = wv[kc * 32 + i];
        float4 a4 = aA[kc];
        float4 b4 = aB[kc];
        acc0 += a4.x * w4.x + a4.y * w4.y + a4.z * w4.z + a4.w * w4.w;
        acc1 += b4.x * w4.x + b4.y * w4.y + b4.z * w4.z + b4.w * w4.w;
    }
    float bi = bias[i];
    float v0 = tanhf(acc0 + bi);
    float v1 = tanhf(acc1 + bi);
    int n0 = blockIdx.x * 16 + mynode;
    hall[n0 * 128 + hall_off + i] = v0;
    hall[(n0 + 1) * 128 + hall_off + i] = v1;
}

// ---------------- final MLP ----------------
static __global__ __launch_bounds__(256) void k_mlp(
    const float* __restrict__ hall, const int* __restrict__ uidx,
    const int* __restrict__ iidx, const float* __restrict__ w1,
    const float* __restrict__ b1, const float* __restrict__ w2,
    const float* __restrict__ b2, float* __restrict__ out) {
    __shared__ float sg[4][256];
    int t = threadIdx.x, wave = t >> 6, lane = t & 63;
    int g = blockIdx.x * 4 + wave;
    int u = uidx[g], it = iidx[g];
    sg[wave][lane]       = hall[u * 128 + lane];
    sg[wave][64 + lane]  = hall[u * 128 + 64 + lane];
    sg[wave][128 + lane] = hall[it * 128 + lane];
    sg[wave][192 + lane] = hall[it * 128 + 64 + lane];
    __syncthreads();
    float a0 = b1[lane], a1 = b1[64 + lane];
#pragma unroll 4
    for (int k = 0; k < 256; k++) {
        float gk = sg[wave][k];
        a0 += gk * w1[k * 128 + lane];
        a1 += gk * w1[k * 128 + 64 + lane];
    }
    float z0 = fmaxf(a0, 0.f), z1 = fmaxf(a1, 0.f);
    float part = z0 * w2[lane] + z1 * w2[64 + lane];
#pragma unroll
    for (int off = 32; off > 0; off >>= 1) part += __shfl_xor(part, off);
    if (lane == 0) out[g] = part + b2[0];
}

// ---------------- launcher ----------------
extern "C" void kernel_launch(void* const* d_in, const int* in_sizes, int n_in,
                              void* d_out, int out_size, void* d_ws, size_t ws_size,
                              hipStream_t stream) {
    const float* x  = (const float*)d_in[0];
    const int*   ei = (const int*)d_in[1];
    const int*   et = (const int*)d_in[2];
    const int*   ui = (const int*)d_in[3];
    const int*   ii = (const int*)d_in[4];
    const float* w1 = (const float*)d_in[21];
    const float* b1 = (const float*)d_in[22];
    const float* w2 = (const float*)d_in[23];
    const float* b2 = (const float*)d_in[24];

    char* ws = (char*)d_ws;
    bool big = ws_size >= 80882944UL;               // 4-layer Wp variant
    if (!big && ws_size < 80821504UL) return;       // proven-safe fallback size
    int*   gcur = (int*)(ws + 0);                   // [196]
    int*   offs = (int*)(ws + 1024);                // [500000]
    int*   cnt  = (int*)(ws + 2001024);             // [500000]
    int*   srcs = (int*)(ws + 4001024);             // [3200000]
    float* x32  = (float*)(ws + 16801024);          // [100000*32]
    float* Wp   = (float*)(ws + 29601024);          // [4*5120] or [5120]
    float* hall = (float*)(ws + (big ? 29682944UL : 29621504UL));  // [100000*128]
    unsigned long long* part = (unsigned long long*)hall;          // alias (dead later)

    hipMemsetAsync(gcur, 0, NBUCK * 4, stream);

    k_part<<<1563, 256, 0, stream>>>(ei, et, gcur, part);
    k_bsort<<<NBUCK, 512, 0, stream>>>(part, gcur, offs, cnt, srcs);
    k_pad<<<12500, 256, 0, stream>>>(x, x32);
    if (big)
        k_wprep4<<<dim3(20, 4), 256, 0, stream>>>(
            (const float*)d_in[5],  (const float*)d_in[7],
            (const float*)d_in[9],  (const float*)d_in[11],
            (const float*)d_in[13], (const float*)d_in[15],
            (const float*)d_in[17], (const float*)d_in[19], Wp);

    for (int l = 0; l < 4; l++) {
        const float* basis = (const float*)d_in[5 + 4 * l];
        const float* comp  = (const float*)d_in[6 + 4 * l];
        const float* root  = (const float*)d_in[7 + 4 * l];
        const float* bias  = (const float*)d_in[8 + 4 * l];
        float* WpL = Wp;
        if (big) WpL = Wp + l * 5120;
        else k_wprep<<<20, 256, 0, stream>>>(basis, root, (l == 0) ? 4 : HID, Wp);
        if (l == 0)
            k_layer<32><<<6250, 256, 0, stream>>>(x32, offs, cnt, srcs, comp, WpL,
                                                  bias, hall, 0);
        else
            k_layer<128><<<6250, 256, 0, stream>>>(hall + (l - 1) * 32, offs, cnt,
                                                   srcs, comp, WpL, bias, hall, l * 32);
    }
    k_mlp<<<1024, 256, 0, stream>>>(hall, ui, ii, w1, b1, w2, b2, (float*)d_out);
}

// Round 5
// 586.573 us; speedup vs baseline: 1.2332x; 1.2332x over previous
//
#include <hip/hip_runtime.h>
#include <hip/hip_bf16.h>

#define N_NODES 100000
#define N_EDGES 3200000
#define N_GRAPHS 4096
#define N_REL 5
#define N_BASES 4
#define HID 32
#define SEG (N_NODES*N_REL)
#define DUMMY N_NODES            // extra node whose feature row is all-zero

#define NBUCK 196                // buckets of 512 dst nodes
#define BCAP  20480              // part-record capacity per bucket (mean 16384, +32 sigma)
#define PBCAP 30720              // padded srcs capacity per bucket (mean ~25.3K worst ~26K)
#define NKEY  2560               // 512 nodes * 5 rels

// ---------------- CSR pass 1: partition edges into dst-range buckets ----------------
static __global__ __launch_bounds__(256) void k_part(const int* __restrict__ ei,
                                                     const int* __restrict__ et,
                                                     int* __restrict__ gcur,
                                                     unsigned long long* __restrict__ part) {
    __shared__ int hcnt[NBUCK];
    __shared__ int lbase[NBUCK];
    int t = threadIdx.x;
    if (t < NBUCK) hcnt[t] = 0;
    __syncthreads();
    int e0 = blockIdx.x * 2048;
    int src[8], bkt[8], lkey[8];
#pragma unroll
    for (int j = 0; j < 8; j++) {
        int e = e0 + j * 256 + t;
        if (e < N_EDGES) {
            int s = ei[e];
            int d = ei[N_EDGES + e];
            int r = et[e];
            src[j] = s; bkt[j] = d >> 9; lkey[j] = ((d & 511) * 5) + r;
            atomicAdd(&hcnt[bkt[j]], 1);
        } else bkt[j] = -1;
    }
    __syncthreads();
    if (t < NBUCK) lbase[t] = atomicAdd(&gcur[t], hcnt[t]);
    __syncthreads();
    if (t < NBUCK) hcnt[t] = 0;   // reuse as intra-block cursor
    __syncthreads();
#pragma unroll
    for (int j = 0; j < 8; j++) {
        if (bkt[j] >= 0) {
            int rank = atomicAdd(&hcnt[bkt[j]], 1);
            int p = lbase[bkt[j]] + rank;
            if (p < BCAP)
                part[(size_t)bkt[j] * BCAP + p] =
                    ((unsigned long long)(unsigned)lkey[j] << 32) | (unsigned)src[j];
        }
    }
}

// ---------------- CSR pass 2: per-bucket counting sort, runs PADDED to 8 ----------------
// offs[seg] = padded run start (fixed per-bucket stride PBCAP); cnt[seg] = real count.
// Pad slots hold DUMMY (zero feature row) -> layer kernel needs no masks at all.
static __global__ __launch_bounds__(512) void k_bsort(const unsigned long long* __restrict__ part,
                                                      const int* __restrict__ gcur,
                                                      int* __restrict__ offs,
                                                      int* __restrict__ cnt,
                                                      int* __restrict__ srcs) {
    __shared__ int lhist[NKEY];      // 10 KB
    __shared__ int lscan[NKEY];      // 10 KB
    __shared__ int sscan[512];       // 2 KB
    __shared__ int lsrc[PBCAP];      // 120 KB
    int b = blockIdx.x;
    int t = threadIdx.x;
    int n = gcur[b]; if (n > BCAP) n = BCAP;
    const unsigned long long* reg = part + (size_t)b * BCAP;

#pragma unroll
    for (int k = t; k < NKEY; k += 512) lhist[k] = 0;
    __syncthreads();
    for (int i = t; i < n; i += 512)
        atomicAdd(&lhist[(int)(reg[i] >> 32)], 1);
    __syncthreads();

    // exclusive scan over PADDED counts (2560 = 512 threads x 5 keys)
    int loc[5]; int s5 = 0;
#pragma unroll
    for (int j = 0; j < 5; j++) { loc[j] = s5; s5 += (lhist[t * 5 + j] + 7) & ~7; }
    sscan[t] = s5;
    __syncthreads();
    for (int off = 1; off < 512; off <<= 1) {
        int x = (t >= off) ? sscan[t - off] : 0;
        __syncthreads();
        sscan[t] += x;
        __syncthreads();
    }
    int excl = sscan[t] - s5;
#pragma unroll
    for (int j = 0; j < 5; j++) lscan[t * 5 + j] = excl + loc[j];
    __syncthreads();
    int ptot = sscan[511]; if (ptot > PBCAP) ptot = PBCAP;

    int base = b * PBCAP;
#pragma unroll
    for (int j = 0; j < 5; j++) {
        int k = t * 5 + j;
        int segid = b * NKEY + k;
        if (segid < SEG) {
            cnt[segid]  = lhist[k];
            offs[segid] = base + lscan[k];
        }
    }
    __syncthreads();
    // reset cursors + dummy-fill padded region
#pragma unroll
    for (int k = t; k < NKEY; k += 512) lhist[k] = 0;
    for (int i = t; i < ptot; i += 512) lsrc[i] = DUMMY;
    __syncthreads();
    for (int i = t; i < n; i += 512) {
        unsigned long long u = reg[i];
        int k = (int)(u >> 32);
        int pos = lscan[k] + atomicAdd(&lhist[k], 1);
        if (pos < PBCAP) lsrc[pos] = (int)(u & 0xffffffffULL);
    }
    __syncthreads();
    for (int i = t; i < ptot; i += 512) srcs[base + i] = lsrc[i];
}

// ---------------- layer-0 padding + zeroing the DUMMY rows (ws is re-poisoned) ----------
static __global__ __launch_bounds__(256) void k_pad(const float* __restrict__ x,
                                                    float* __restrict__ x32,
                                                    float* __restrict__ hall) {
    int tid = blockIdx.x * 256 + threadIdx.x;
    if (tid < N_NODES * 32) {
        int nd = tid >> 5, ii = tid & 31;
        x32[tid] = (ii < 4) ? x[(nd << 2) + ii] : 0.f;
    } else {
        int r = tid - N_NODES * 32;
        if (r < 32) x32[N_NODES * 32 + r] = 0.f;                  // dummy row, layer 0
        else if (r < 160) hall[N_NODES * 128 + (r - 32)] = 0.f;   // dummy row, layers 1-3
    }
}

// ---------------- weight prep: all 4 layers in one launch ----------------
static __global__ __launch_bounds__(256) void k_wprep4(
    const float* __restrict__ ba0, const float* __restrict__ ro0,
    const float* __restrict__ ba1, const float* __restrict__ ro1,
    const float* __restrict__ ba2, const float* __restrict__ ro2,
    const float* __restrict__ ba3, const float* __restrict__ ro3,
    float* __restrict__ Wp) {
    int l = blockIdx.y;
    const float* basis = (l == 0) ? ba0 : (l == 1) ? ba1 : (l == 2) ? ba2 : ba3;
    const float* root  = (l == 0) ? ro0 : (l == 1) ? ro1 : (l == 2) ? ro2 : ro3;
    int in_c = (l == 0) ? 4 : HID;
    int idx = blockIdx.x * 256 + threadIdx.x;   // < 5120
    int kc = idx >> 7, rem = idx & 127;
    int o = rem >> 2, j = rem & 3;
    int k = kc * 4 + j;
    float v;
    if (k < 128) {
        int b = k >> 5, ii = k & 31;
        v = (ii < in_c) ? basis[(b * in_c + ii) * HID + o] : 0.f;
    } else {
        int ii = k - 128;
        v = (ii < in_c) ? root[ii * HID + o] : 0.f;
    }
    Wp[l * 5120 + kc * 128 + o * 4 + j] = v;
}

// ---------------- fused RGCN layer ----------------
// Half-wave = 1 node (lane = dim), 2 nodes sequential -> 16 nodes/block.
// Runs are 8-padded with DUMMY (zero row): inner loop per 8 edges is
// 2 broadcast dwordx4 srcs loads + 8 independent gathers + tree-sum into a
// plain run sum S. Weight fold comp[r][b]*(S/c_r) happens once per run.
// No masks, no shuffles, no LDS in phase 1.
template <int STRIDE>
static __global__ __launch_bounds__(256, 4) void k_layer(
    const float* __restrict__ hin, const int* __restrict__ offs,
    const int* __restrict__ cnt, const int* __restrict__ srcs,
    const float* __restrict__ comp, const float* __restrict__ Wp,
    const float* __restrict__ bias, float* __restrict__ hall, int hall_off) {
    __shared__ __align__(16) float sAgg[16][160];   // 10 KB
    int t = threadIdx.x;
    int wave = t >> 6, hw = t >> 5, i = t & 31;

    float4 cw0 = *(const float4*)(comp + 0);
    float4 cw1 = *(const float4*)(comp + 4);
    float4 cw2 = *(const float4*)(comp + 8);
    float4 cw3 = *(const float4*)(comp + 12);
    float4 cw4 = *(const float4*)(comp + 16);

    int nb = blockIdx.x * 16;                       // N_NODES = 6250*16 exactly
    for (int nn = 0; nn < 2; nn++) {
        int nl = hw * 2 + nn;
        int n = nb + nl;
        int s5 = n * N_REL;
        int B  = offs[s5];
        int o1 = offs[s5 + 1], o2 = offs[s5 + 2], o3 = offs[s5 + 3], o4 = offs[s5 + 4];
        int c0 = cnt[s5], c1 = cnt[s5 + 1], c2 = cnt[s5 + 2],
            c3 = cnt[s5 + 3], c4 = cnt[s5 + 4];
        int cr_[5] = {c0, c1, c2, c3, c4};
        int pr_[5] = {o1 - B, o2 - o1, o3 - o2, o4 - o3, (c4 + 7) & ~7};
        float a0 = 0.f, a1 = 0.f, a2 = 0.f, a3 = 0.f;
        int sr = B;
#pragma unroll
        for (int r = 0; r < 5; r++) {
            int cr = cr_[r], pr = pr_[r];
            if (cr > 0) {
                float S = 0.f;
                for (int s8 = 0; s8 < pr; s8 += 8) {
                    const int* sp = srcs + sr + s8;          // 32B-aligned
                    int4 ea = *(const int4*)(sp);            // broadcast dwordx4
                    int4 eb = *(const int4*)(sp + 4);
                    float h0 = hin[ea.x * STRIDE + i];
                    float h1 = hin[ea.y * STRIDE + i];
                    float h2 = hin[ea.z * STRIDE + i];
                    float h3 = hin[ea.w * STRIDE + i];
                    float h4 = hin[eb.x * STRIDE + i];
                    float h5 = hin[eb.y * STRIDE + i];
                    float h6 = hin[eb.z * STRIDE + i];
                    float h7 = hin[eb.w * STRIDE + i];
                    S += ((h0 + h1) + (h2 + h3)) + ((h4 + h5) + (h6 + h7));
                }
                float Sc = S * __builtin_amdgcn_rcpf((float)cr);
                float4 cw = (r == 0) ? cw0 : (r == 1) ? cw1 : (r == 2) ? cw2
                          : (r == 3) ? cw3 : cw4;            // resolved at unroll
                a0 += cw.x * Sc; a1 += cw.y * Sc;
                a2 += cw.z * Sc; a3 += cw.w * Sc;
            }
            sr += pr;
        }
        sAgg[nl][i]       = a0;
        sAgg[nl][32 + i]  = a1;
        sAgg[nl][64 + i]  = a2;
        sAgg[nl][96 + i]  = a3;
        sAgg[nl][128 + i] = hin[n * STRIDE + i];   // self feature
    }
    __syncthreads();

    // phase 2: K=160 matvec, W float4 from global (L1-resident 20 KB)
    int half = (t >> 5) & 1;
    int mynode = wave * 4 + half * 2;
    const float4* wv = (const float4*)Wp;
    const float4* aA = (const float4*)&sAgg[mynode][0];
    const float4* aB = (const float4*)&sAgg[mynode + 1][0];
    float acc0 = 0.f, acc1 = 0.f;
#pragma unroll 8
    for (int kc = 0; kc < 40; kc++) {
        float4 w4 = wv[kc * 32 + i];
        float4 a4 = aA[kc];
        float4 b4 = aB[kc];
        acc0 += a4.x * w4.x + a4.y * w4.y + a4.z * w4.z + a4.w * w4.w;
        acc1 += b4.x * w4.x + b4.y * w4.y + b4.z * w4.z + b4.w * w4.w;
    }
    float bi = bias[i];
    float v0 = tanhf(acc0 + bi);
    float v1 = tanhf(acc1 + bi);
    int n0 = blockIdx.x * 16 + mynode;
    hall[n0 * 128 + hall_off + i] = v0;
    hall[(n0 + 1) * 128 + hall_off + i] = v1;
}

// ---------------- final MLP ----------------
static __global__ __launch_bounds__(256) void k_mlp(
    const float* __restrict__ hall, const int* __restrict__ uidx,
    const int* __restrict__ iidx, const float* __restrict__ w1,
    const float* __restrict__ b1, const float* __restrict__ w2,
    const float* __restrict__ b2, float* __restrict__ out) {
    __shared__ float sg[4][256];
    int t = threadIdx.x, wave = t >> 6, lane = t & 63;
    int g = blockIdx.x * 4 + wave;
    int u = uidx[g], it = iidx[g];
    sg[wave][lane]       = hall[u * 128 + lane];
    sg[wave][64 + lane]  = hall[u * 128 + 64 + lane];
    sg[wave][128 + lane] = hall[it * 128 + lane];
    sg[wave][192 + lane] = hall[it * 128 + 64 + lane];
    __syncthreads();
    float a0 = b1[lane], a1 = b1[64 + lane];
#pragma unroll 4
    for (int k = 0; k < 256; k++) {
        float gk = sg[wave][k];
        a0 += gk * w1[k * 128 + lane];
        a1 += gk * w1[k * 128 + 64 + lane];
    }
    float z0 = fmaxf(a0, 0.f), z1 = fmaxf(a1, 0.f);
    float part = z0 * w2[lane] + z1 * w2[64 + lane];
#pragma unroll
    for (int off = 32; off > 0; off >>= 1) part += __shfl_xor(part, off);
    if (lane == 0) out[g] = part + b2[0];
}

// ---------------- launcher ----------------
extern "C" void kernel_launch(void* const* d_in, const int* in_sizes, int n_in,
                              void* d_out, int out_size, void* d_ws, size_t ws_size,
                              hipStream_t stream) {
    const float* x  = (const float*)d_in[0];
    const int*   ei = (const int*)d_in[1];
    const int*   et = (const int*)d_in[2];
    const int*   ui = (const int*)d_in[3];
    const int*   ii = (const int*)d_in[4];
    const float* w1 = (const float*)d_in[21];
    const float* b1 = (const float*)d_in[22];
    const float* w2 = (const float*)d_in[23];
    const float* b2 = (const float*)d_in[24];

    // workspace layout (bytes, 128-aligned). ws_size >= 95,620,608 proven in R1.
    char* ws = (char*)d_ws;
    if (ws_size < 92168064UL) return;
    int*   gcur = (int*)(ws + 0);               // [196]
    int*   offs = (int*)(ws + 1024);            // [500000]
    int*   cnt  = (int*)(ws + 2001024);         // [500000]
    int*   srcs = (int*)(ws + 4001024);         // [196*30720] padded
    float* x32  = (float*)(ws + 28085504);      // [100001*32] (+dummy row)
    float* Wp   = (float*)(ws + 40885632);      // [4*5120]
    float* hall = (float*)(ws + 40967552);      // [100001*128] (+dummy row)
    unsigned long long* part = (unsigned long long*)hall;  // alias, 32.1 MB (dead later)

    hipMemsetAsync(gcur, 0, NBUCK * 4, stream);

    k_part<<<1563, 256, 0, stream>>>(ei, et, gcur, part);
    k_bsort<<<NBUCK, 512, 0, stream>>>(part, gcur, offs, cnt, srcs);
    k_pad<<<12501, 256, 0, stream>>>(x, x32, hall);
    k_wprep4<<<dim3(20, 4), 256, 0, stream>>>(
        (const float*)d_in[5],  (const float*)d_in[7],
        (const float*)d_in[9],  (const float*)d_in[11],
        (const float*)d_in[13], (const float*)d_in[15],
        (const float*)d_in[17], (const float*)d_in[19], Wp);

    for (int l = 0; l < 4; l++) {
        const float* comp = (const float*)d_in[6 + 4 * l];
        const float* bias = (const float*)d_in[8 + 4 * l];
        float* WpL = Wp + l * 5120;
        if (l == 0)
            k_layer<32><<<6250, 256, 0, stream>>>(x32, offs, cnt, srcs, comp, WpL,
                                                  bias, hall, 0);
        else
            k_layer<128><<<6250, 256, 0, stream>>>(hall + (l - 1) * 32, offs, cnt,
                                                   srcs, comp, WpL, bias, hall, l * 32);
    }
    k_mlp<<<1024, 256, 0, stream>>>(hall, ui, ii, w1, b1, w2, b2, (float*)d_out);
}

// Round 6
// 550.270 us; speedup vs baseline: 1.3146x; 1.0660x over previous
//
#include <hip/hip_runtime.h>
#include <hip/hip_bf16.h>
#include <hip/hip_fp16.h>

#define N_NODES 100000
#define N_EDGES 3200000
#define N_GRAPHS 4096
#define N_REL 5
#define N_BASES 4
#define HID 32
#define SEG (N_NODES*N_REL)
#define DUMMY N_NODES            // extra node whose fp16 feature row is all-zero

#define NBUCK 196                // buckets of 512 dst nodes
#define BCAP  20480              // part-record capacity per bucket
#define PBCAP 30720              // padded srcs capacity per bucket
#define NKEY  2560               // 512 nodes * 5 rels

// ---------------- CSR pass 1: partition edges into dst-range buckets ----------------
// 16 edges/thread (4096/block, 782 blocks): half the global-atomic rounds on the
// 196 cursors vs R5, ~21-record write runs per bucket per block.
static __global__ __launch_bounds__(256) void k_part(const int* __restrict__ ei,
                                                     const int* __restrict__ et,
                                                     int* __restrict__ gcur,
                                                     unsigned long long* __restrict__ part) {
    __shared__ int hcnt[NBUCK];
    __shared__ int lbase[NBUCK];
    int t = threadIdx.x;
    if (t < NBUCK) hcnt[t] = 0;
    __syncthreads();
    int e0 = blockIdx.x * 4096;
    int src[16], bkt[16], lkey[16];
#pragma unroll
    for (int j = 0; j < 16; j++) {
        int e = e0 + j * 256 + t;
        if (e < N_EDGES) {
            int s = ei[e];
            int d = ei[N_EDGES + e];
            int r = et[e];
            src[j] = s; bkt[j] = d >> 9; lkey[j] = ((d & 511) * 5) + r;
            atomicAdd(&hcnt[bkt[j]], 1);
        } else bkt[j] = -1;
    }
    __syncthreads();
    if (t < NBUCK) lbase[t] = atomicAdd(&gcur[t], hcnt[t]);
    __syncthreads();
    if (t < NBUCK) hcnt[t] = 0;   // reuse as intra-block cursor
    __syncthreads();
#pragma unroll
    for (int j = 0; j < 16; j++) {
        if (bkt[j] >= 0) {
            int rank = atomicAdd(&hcnt[bkt[j]], 1);
            int p = lbase[bkt[j]] + rank;
            if (p < BCAP)
                part[(size_t)bkt[j] * BCAP + p] =
                    ((unsigned long long)(unsigned)lkey[j] << 32) | (unsigned)src[j];
        }
    }
}

// ---------------- CSR pass 2: per-bucket counting sort, runs PADDED to 8 ----------------
static __global__ __launch_bounds__(512) void k_bsort(const unsigned long long* __restrict__ part,
                                                      const int* __restrict__ gcur,
                                                      int* __restrict__ offs,
                                                      int* __restrict__ cnt,
                                                      int* __restrict__ srcs) {
    __shared__ int lhist[NKEY];      // 10 KB
    __shared__ int lscan[NKEY];      // 10 KB
    __shared__ int sscan[512];       // 2 KB
    __shared__ int lsrc[PBCAP];      // 120 KB
    int b = blockIdx.x;
    int t = threadIdx.x;
    int n = gcur[b]; if (n > BCAP) n = BCAP;
    const unsigned long long* reg = part + (size_t)b * BCAP;

#pragma unroll
    for (int k = t; k < NKEY; k += 512) lhist[k] = 0;
    __syncthreads();
    for (int i = t; i < n; i += 512)
        atomicAdd(&lhist[(int)(reg[i] >> 32)], 1);
    __syncthreads();

    // exclusive scan over PADDED counts (2560 = 512 threads x 5 keys)
    int loc[5]; int s5 = 0;
#pragma unroll
    for (int j = 0; j < 5; j++) { loc[j] = s5; s5 += (lhist[t * 5 + j] + 7) & ~7; }
    sscan[t] = s5;
    __syncthreads();
    for (int off = 1; off < 512; off <<= 1) {
        int x = (t >= off) ? sscan[t - off] : 0;
        __syncthreads();
        sscan[t] += x;
        __syncthreads();
    }
    int excl = sscan[t] - s5;
#pragma unroll
    for (int j = 0; j < 5; j++) lscan[t * 5 + j] = excl + loc[j];
    __syncthreads();
    int ptot = sscan[511]; if (ptot > PBCAP) ptot = PBCAP;

    int base = b * PBCAP;
#pragma unroll
    for (int j = 0; j < 5; j++) {
        int k = t * 5 + j;
        int segid = b * NKEY + k;
        if (segid < SEG) {
            cnt[segid]  = lhist[k];
            offs[segid] = base + lscan[k];
        }
    }
    __syncthreads();
    // reset cursors + dummy-fill padded region
#pragma unroll
    for (int k = t; k < NKEY; k += 512) lhist[k] = 0;
    for (int i = t; i < ptot; i += 512) lsrc[i] = DUMMY;
    __syncthreads();
    for (int i = t; i < n; i += 512) {
        unsigned long long u = reg[i];
        int k = (int)(u >> 32);
        int pos = lscan[k] + atomicAdd(&lhist[k], 1);
        if (pos < PBCAP) lsrc[pos] = (int)(u & 0xffffffffULL);
    }
    __syncthreads();
    for (int i = t; i < ptot; i += 512) srcs[base + i] = lsrc[i];
}

// ---------------- fp16 layer-0 table + dummy rows + srcs slack ----------------
static __global__ __launch_bounds__(256) void k_pad(const float* __restrict__ x,
                                                    __half* __restrict__ ht0,
                                                    __half* __restrict__ ht1,
                                                    int* __restrict__ srcs) {
    int tid = blockIdx.x * 256 + threadIdx.x;
    if (tid < (N_NODES + 1) * 32) {
        int nd = tid >> 5, ii = tid & 31;
        float v = (nd < N_NODES && ii < 4) ? x[(nd << 2) + ii] : 0.f;
        ht0[tid] = __float2half(v);
    } else {
        int r = tid - (N_NODES + 1) * 32;
        if (r < 32) ht1[N_NODES * 32 + r] = __float2half(0.f);   // ht1 dummy row
        else if (r < 48) srcs[NBUCK * PBCAP + (r - 32)] = DUMMY; // srcs slack
    }
}

// ---------------- weight prep: all 4 layers in one launch ----------------
static __global__ __launch_bounds__(256) void k_wprep4(
    const float* __restrict__ ba0, const float* __restrict__ ro0,
    const float* __restrict__ ba1, const float* __restrict__ ro1,
    const float* __restrict__ ba2, const float* __restrict__ ro2,
    const float* __restrict__ ba3, const float* __restrict__ ro3,
    float* __restrict__ Wp) {
    int l = blockIdx.y;
    const float* basis = (l == 0) ? ba0 : (l == 1) ? ba1 : (l == 2) ? ba2 : ba3;
    const float* root  = (l == 0) ? ro0 : (l == 1) ? ro1 : (l == 2) ? ro2 : ro3;
    int in_c = (l == 0) ? 4 : HID;
    int idx = blockIdx.x * 256 + threadIdx.x;   // < 5120
    int kc = idx >> 7, rem = idx & 127;
    int o = rem >> 2, j = rem & 3;
    int k = kc * 4 + j;
    float v;
    if (k < 128) {
        int b = k >> 5, ii = k & 31;
        v = (ii < in_c) ? basis[(b * in_c + ii) * HID + o] : 0.f;
    } else {
        int ii = k - 128;
        v = (ii < in_c) ? root[ii * HID + o] : 0.f;
    }
    Wp[l * 5120 + kc * 128 + o * 4 + j] = v;
}

// ---------------- fused RGCN layer ----------------
// Half-wave = 2 nodes (A,B), lane = dim. Per relation r, BOTH nodes' first
// 8-slot gather batches are issued back-to-back (16 independent fp16 gathers
// in flight per wave) before any consumption; residual batches (pr>8, ~20%)
// follow. Empty runs (0.17%) gather harmlessly (valid/slack srcs) and are
// zeroed at the fold. Gather table is DENSE fp16 [100001x32].
#define G8(S, ev0, ev1) { \
    float h0 = __half2float(hin[(ev0).x * 32 + i]); \
    float h1 = __half2float(hin[(ev0).y * 32 + i]); \
    float h2 = __half2float(hin[(ev0).z * 32 + i]); \
    float h3 = __half2float(hin[(ev0).w * 32 + i]); \
    float h4 = __half2float(hin[(ev1).x * 32 + i]); \
    float h5 = __half2float(hin[(ev1).y * 32 + i]); \
    float h6 = __half2float(hin[(ev1).z * 32 + i]); \
    float h7 = __half2float(hin[(ev1).w * 32 + i]); \
    S += ((h0 + h1) + (h2 + h3)) + ((h4 + h5) + (h6 + h7)); }

static __global__ __launch_bounds__(256, 6) void k_layer(
    const __half* __restrict__ hin, const int* __restrict__ offs,
    const int* __restrict__ cnt, const int* __restrict__ srcs,
    const float* __restrict__ comp, const float* __restrict__ Wp,
    const float* __restrict__ bias, __half* __restrict__ hout,
    float* __restrict__ hall, int hall_off) {
    __shared__ __align__(16) float sAgg[16][160];   // 10 KB
    int t = threadIdx.x;
    int wave = t >> 6, hw = t >> 5, i = t & 31;

    float4 cw0 = *(const float4*)(comp + 0);        // SGPR-resident
    float4 cw1 = *(const float4*)(comp + 4);
    float4 cw2 = *(const float4*)(comp + 8);
    float4 cw3 = *(const float4*)(comp + 12);
    float4 cw4 = *(const float4*)(comp + 16);

    int nA = blockIdx.x * 16 + hw * 2;              // N_NODES = 6250*16
    int nB = nA + 1;
    int sA = nA * N_REL, sB = nB * N_REL;
    int oA[5], oB[5];
#pragma unroll
    for (int r = 0; r < 5; r++) { oA[r] = offs[sA + r]; oB[r] = offs[sB + r]; }
    int cA4 = cnt[sA + 4], cB4 = cnt[sB + 4];
    int eAe = oA[4] + ((cA4 + 7) & ~7);             // node A padded end
    int eBe = oB[4] + ((cB4 + 7) & ~7);

    float selfA = __half2float(hin[nA * 32 + i]);
    float selfB = __half2float(hin[nB * 32 + i]);
    float aA0 = 0.f, aA1 = 0.f, aA2 = 0.f, aA3 = 0.f;
    float aB0 = 0.f, aB1 = 0.f, aB2 = 0.f, aB3 = 0.f;

#pragma unroll
    for (int r = 0; r < 5; r++) {
        int pA = oA[r], pB = oB[r];
        int prA = ((r < 4) ? oA[r + 1] : eAe) - pA;
        int prB = ((r < 4) ? oB[r + 1] : eBe) - pB;
        const int* spA = srcs + pA;
        const int* spB = srcs + pB;
        int4 va0 = *(const int4*)(spA);             // both nodes' src batches
        int4 va1 = *(const int4*)(spA + 4);
        int4 vb0 = *(const int4*)(spB);
        int4 vb1 = *(const int4*)(spB + 4);
        float SA = 0.f, SB = 0.f;
        G8(SA, va0, va1);                           // 16 gathers issued before
        G8(SB, vb0, vb1);                           // the adds block on vmcnt
        for (int s8 = 8; s8 < prA; s8 += 8) {       // residual (rare)
            int4 e0 = *(const int4*)(spA + s8);
            int4 e1 = *(const int4*)(spA + s8 + 4);
            G8(SA, e0, e1);
        }
        for (int s8 = 8; s8 < prB; s8 += 8) {
            int4 e0 = *(const int4*)(spB + s8);
            int4 e1 = *(const int4*)(spB + s8 + 4);
            G8(SB, e0, e1);
        }
        int crA = cnt[sA + r], crB = cnt[sB + r];
        float ScA = (crA > 0) ? SA * __builtin_amdgcn_rcpf((float)crA) : 0.f;
        float ScB = (crB > 0) ? SB * __builtin_amdgcn_rcpf((float)crB) : 0.f;
        float4 cw = (r == 0) ? cw0 : (r == 1) ? cw1 : (r == 2) ? cw2
                  : (r == 3) ? cw3 : cw4;           // resolved at unroll
        aA0 += cw.x * ScA; aA1 += cw.y * ScA; aA2 += cw.z * ScA; aA3 += cw.w * ScA;
        aB0 += cw.x * ScB; aB1 += cw.y * ScB; aB2 += cw.z * ScB; aB3 += cw.w * ScB;
    }
    int nlA = hw * 2, nlB = nlA + 1;
    sAgg[nlA][i]       = aA0;  sAgg[nlB][i]       = aB0;
    sAgg[nlA][32 + i]  = aA1;  sAgg[nlB][32 + i]  = aB1;
    sAgg[nlA][64 + i]  = aA2;  sAgg[nlB][64 + i]  = aB2;
    sAgg[nlA][96 + i]  = aA3;  sAgg[nlB][96 + i]  = aB3;
    sAgg[nlA][128 + i] = selfA; sAgg[nlB][128 + i] = selfB;
    __syncthreads();

    // phase 2: K=160 matvec, W float4 from global (L1-resident 20 KB)
    int half = (t >> 5) & 1;
    int mynode = wave * 4 + half * 2;
    const float4* wv = (const float4*)Wp;
    const float4* aA = (const float4*)&sAgg[mynode][0];
    const float4* aB = (const float4*)&sAgg[mynode + 1][0];
    float acc0 = 0.f, acc1 = 0.f;
#pragma unroll 8
    for (int kc = 0; kc < 40; kc++) {
        float4 w4 = wv[kc * 32 + i];
        float4 a4 = aA[kc];
        float4 b4 = aB[kc];
        acc0 += a4.x * w4.x + a4.y * w4.y + a4.z * w4.z + a4.w * w4.w;
        acc1 += b4.x * w4.x + b4.y * w4.y + b4.z * w4.z + b4.w * w4.w;
    }
    float bi = bias[i];
    float v0 = tanhf(acc0 + bi);
    float v1 = tanhf(acc1 + bi);
    int n0 = blockIdx.x * 16 + mynode;
    hall[n0 * 128 + hall_off + i] = v0;             // fp32 for the MLP
    hall[(n0 + 1) * 128 + hall_off + i] = v1;
    hout[n0 * 32 + i] = __float2half(v0);           // fp16 gather table
    hout[(n0 + 1) * 32 + i] = __float2half(v1);
}

// ---------------- final MLP: 16 graphs/block (w1 global traffic /4) ----------------
static __global__ __launch_bounds__(256) void k_mlp(
    const float* __restrict__ hall, const int* __restrict__ uidx,
    const int* __restrict__ iidx, const float* __restrict__ w1,
    const float* __restrict__ b1, const float* __restrict__ w2,
    const float* __restrict__ b2, float* __restrict__ out) {
    __shared__ float sg[4][4][256];                 // 16 KB
    int t = threadIdx.x, wave = t >> 6, lane = t & 63;
    int g0 = blockIdx.x * 16 + wave * 4;
#pragma unroll
    for (int gg = 0; gg < 4; gg++) {
        int g = g0 + gg;
        int u = uidx[g], it = iidx[g];
        sg[wave][gg][lane]       = hall[u * 128 + lane];
        sg[wave][gg][64 + lane]  = hall[u * 128 + 64 + lane];
        sg[wave][gg][128 + lane] = hall[it * 128 + lane];
        sg[wave][gg][192 + lane] = hall[it * 128 + 64 + lane];
    }
    __syncthreads();
    float a0[4], a1[4];
#pragma unroll
    for (int gg = 0; gg < 4; gg++) { a0[gg] = b1[lane]; a1[gg] = b1[64 + lane]; }
#pragma unroll 4
    for (int k = 0; k < 256; k++) {
        float wa = w1[k * 128 + lane];
        float wb = w1[k * 128 + 64 + lane];
#pragma unroll
        for (int gg = 0; gg < 4; gg++) {
            float gk = sg[wave][gg][k];
            a0[gg] += gk * wa; a1[gg] += gk * wb;
        }
    }
    float w2a = w2[lane], w2b = w2[64 + lane], bb = b2[0];
#pragma unroll
    for (int gg = 0; gg < 4; gg++) {
        float z0 = fmaxf(a0[gg], 0.f), z1 = fmaxf(a1[gg], 0.f);
        float part = z0 * w2a + z1 * w2b;
#pragma unroll
        for (int off = 32; off > 0; off >>= 1) part += __shfl_xor(part, off);
        if (lane == 0) out[g0 + gg] = part + bb;
    }
}

// ---------------- launcher ----------------
extern "C" void kernel_launch(void* const* d_in, const int* in_sizes, int n_in,
                              void* d_out, int out_size, void* d_ws, size_t ws_size,
                              hipStream_t stream) {
    const float* x  = (const float*)d_in[0];
    const int*   ei = (const int*)d_in[1];
    const int*   et = (const int*)d_in[2];
    const int*   ui = (const int*)d_in[3];
    const int*   ii = (const int*)d_in[4];
    const float* w1 = (const float*)d_in[21];
    const float* b1 = (const float*)d_in[22];
    const float* w2 = (const float*)d_in[23];
    const float* b2 = (const float*)d_in[24];

    // workspace layout (bytes, 128-aligned). ws_size >= 95,620,608 proven in R1.
    char* ws = (char*)d_ws;
    if (ws_size < 92167680UL) return;
    int*    gcur = (int*)(ws + 0);              // [196]
    int*    offs = (int*)(ws + 1024);           // [500000]
    int*    cnt  = (int*)(ws + 2001024);        // [500000]
    int*    srcs = (int*)(ws + 4001024);        // [196*30720] + 16 slack
    __half* ht0  = (__half*)(ws + 28085568);    // [100001*32] fp16
    __half* ht1  = (__half*)(ws + 34485632);    // [100001*32] fp16
    float*  Wp   = (float*)(ws + 40885760);     // [4*5120]
    float*  hall = (float*)(ws + 40967680);     // [100000*128] fp32
    unsigned long long* part = (unsigned long long*)hall;  // alias, 32.1 MB (dead later)

    hipMemsetAsync(gcur, 0, NBUCK * 4, stream);

    k_part<<<782, 256, 0, stream>>>(ei, et, gcur, part);
    k_bsort<<<NBUCK, 512, 0, stream>>>(part, gcur, offs, cnt, srcs);
    k_pad<<<12501, 256, 0, stream>>>(x, ht0, ht1, srcs);
    k_wprep4<<<dim3(20, 4), 256, 0, stream>>>(
        (const float*)d_in[5],  (const float*)d_in[7],
        (const float*)d_in[9],  (const float*)d_in[11],
        (const float*)d_in[13], (const float*)d_in[15],
        (const float*)d_in[17], (const float*)d_in[19], Wp);

    __half* tab[2] = {ht0, ht1};
    for (int l = 0; l < 4; l++) {
        const float* comp = (const float*)d_in[6 + 4 * l];
        const float* bias = (const float*)d_in[8 + 4 * l];
        k_layer<<<6250, 256, 0, stream>>>(tab[l & 1], offs, cnt, srcs, comp,
                                          Wp + l * 5120, bias, tab[(l + 1) & 1],
                                          hall, l * 32);
    }
    k_mlp<<<256, 256, 0, stream>>>(hall, ui, ii, w1, b1, w2, b2, (float*)d_out);
}

// Round 7
// 485.984 us; speedup vs baseline: 1.4885x; 1.1323x over previous
//
#include <hip/hip_runtime.h>
#include <hip/hip_bf16.h>
#include <hip/hip_fp16.h>

#define N_NODES 100000
#define N_EDGES 3200000
#define N_GRAPHS 4096
#define N_REL 5
#define N_BASES 4
#define HID 32
#define SEG (N_NODES*N_REL)
#define DUMMY N_NODES            // extra node whose fp16 feature row is all-zero

#define NBUCK 196                // buckets of 512 dst nodes
#define BCAP  20480              // part-record capacity per bucket
#define PBCAP 30720              // padded srcs capacity per bucket
#define NKEY  2560               // 512 nodes * 5 rels

// ---------------- CSR pass 1: partition edges into dst-range buckets ----------------
static __global__ __launch_bounds__(256) void k_part(const int* __restrict__ ei,
                                                     const int* __restrict__ et,
                                                     int* __restrict__ gcur,
                                                     unsigned long long* __restrict__ part) {
    __shared__ int hcnt[NBUCK];
    __shared__ int lbase[NBUCK];
    int t = threadIdx.x;
    if (t < NBUCK) hcnt[t] = 0;
    __syncthreads();
    int e0 = blockIdx.x * 4096;
    int src[16], bkt[16], lkey[16];
#pragma unroll
    for (int j = 0; j < 16; j++) {
        int e = e0 + j * 256 + t;
        if (e < N_EDGES) {
            int s = ei[e];
            int d = ei[N_EDGES + e];
            int r = et[e];
            src[j] = s; bkt[j] = d >> 9; lkey[j] = ((d & 511) * 5) + r;
            atomicAdd(&hcnt[bkt[j]], 1);
        } else bkt[j] = -1;
    }
    __syncthreads();
    if (t < NBUCK) lbase[t] = atomicAdd(&gcur[t], hcnt[t]);
    __syncthreads();
    if (t < NBUCK) hcnt[t] = 0;   // reuse as intra-block cursor
    __syncthreads();
#pragma unroll
    for (int j = 0; j < 16; j++) {
        if (bkt[j] >= 0) {
            int rank = atomicAdd(&hcnt[bkt[j]], 1);
            int p = lbase[bkt[j]] + rank;
            if (p < BCAP)
                part[(size_t)bkt[j] * BCAP + p] =
                    ((unsigned long long)(unsigned)lkey[j] << 32) | (unsigned)src[j];
        }
    }
}

// ---------------- CSR pass 2: per-bucket counting sort, runs PADDED to 8 ----------------
static __global__ __launch_bounds__(512) void k_bsort(const unsigned long long* __restrict__ part,
                                                      const int* __restrict__ gcur,
                                                      int* __restrict__ offs,
                                                      int* __restrict__ cnt,
                                                      int* __restrict__ srcs) {
    __shared__ int lhist[NKEY];      // 10 KB
    __shared__ int lscan[NKEY];      // 10 KB
    __shared__ int sscan[512];       // 2 KB
    __shared__ int lsrc[PBCAP];      // 120 KB
    int b = blockIdx.x;
    int t = threadIdx.x;
    int n = gcur[b]; if (n > BCAP) n = BCAP;
    const unsigned long long* reg = part + (size_t)b * BCAP;

#pragma unroll
    for (int k = t; k < NKEY; k += 512) lhist[k] = 0;
    __syncthreads();
    for (int i = t; i < n; i += 512)
        atomicAdd(&lhist[(int)(reg[i] >> 32)], 1);
    __syncthreads();

    // exclusive scan over PADDED counts (2560 = 512 threads x 5 keys)
    int loc[5]; int s5 = 0;
#pragma unroll
    for (int j = 0; j < 5; j++) { loc[j] = s5; s5 += (lhist[t * 5 + j] + 7) & ~7; }
    sscan[t] = s5;
    __syncthreads();
    for (int off = 1; off < 512; off <<= 1) {
        int x = (t >= off) ? sscan[t - off] : 0;
        __syncthreads();
        sscan[t] += x;
        __syncthreads();
    }
    int excl = sscan[t] - s5;
#pragma unroll
    for (int j = 0; j < 5; j++) lscan[t * 5 + j] = excl + loc[j];
    __syncthreads();
    int ptot = sscan[511]; if (ptot > PBCAP) ptot = PBCAP;

    int base = b * PBCAP;
#pragma unroll
    for (int j = 0; j < 5; j++) {
        int k = t * 5 + j;
        int segid = b * NKEY + k;
        if (segid < SEG) {
            cnt[segid]  = lhist[k];
            offs[segid] = base + lscan[k];
        }
    }
    __syncthreads();
    // reset cursors + dummy-fill padded region
#pragma unroll
    for (int k = t; k < NKEY; k += 512) lhist[k] = 0;
    for (int i = t; i < ptot; i += 512) lsrc[i] = DUMMY;
    __syncthreads();
    for (int i = t; i < n; i += 512) {
        unsigned long long u = reg[i];
        int k = (int)(u >> 32);
        int pos = lscan[k] + atomicAdd(&lhist[k], 1);
        if (pos < PBCAP) lsrc[pos] = (int)(u & 0xffffffffULL);
    }
    __syncthreads();
    for (int i = t; i < ptot; i += 512) srcs[base + i] = lsrc[i];
}

// ---------------- fp16 layer-0 table + dummy rows + srcs slack ----------------
static __global__ __launch_bounds__(256) void k_pad(const float* __restrict__ x,
                                                    __half* __restrict__ ht0,
                                                    __half* __restrict__ ht1,
                                                    int* __restrict__ srcs) {
    int tid = blockIdx.x * 256 + threadIdx.x;
    if (tid < (N_NODES + 1) * 32) {
        int nd = tid >> 5, ii = tid & 31;
        float v = (nd < N_NODES && ii < 4) ? x[(nd << 2) + ii] : 0.f;
        ht0[tid] = __float2half(v);
    } else {
        int r = tid - (N_NODES + 1) * 32;
        if (r < 32) ht1[N_NODES * 32 + r] = __float2half(0.f);   // ht1 dummy row
        else if (r < 48) srcs[NBUCK * PBCAP + (r - 32)] = DUMMY; // srcs slack
    }
}

// ---------------- weight prep: all 4 layers in one launch ----------------
static __global__ __launch_bounds__(256) void k_wprep4(
    const float* __restrict__ ba0, const float* __restrict__ ro0,
    const float* __restrict__ ba1, const float* __restrict__ ro1,
    const float* __restrict__ ba2, const float* __restrict__ ro2,
    const float* __restrict__ ba3, const float* __restrict__ ro3,
    float* __restrict__ Wp) {
    int l = blockIdx.y;
    const float* basis = (l == 0) ? ba0 : (l == 1) ? ba1 : (l == 2) ? ba2 : ba3;
    const float* root  = (l == 0) ? ro0 : (l == 1) ? ro1 : (l == 2) ? ro2 : ro3;
    int in_c = (l == 0) ? 4 : HID;
    int idx = blockIdx.x * 256 + threadIdx.x;   // < 5120
    int kc = idx >> 7, rem = idx & 127;
    int o = rem >> 2, j = rem & 3;
    int k = kc * 4 + j;
    float v;
    if (k < 128) {
        int b = k >> 5, ii = k & 31;
        v = (ii < in_c) ? basis[(b * in_c + ii) * HID + o] : 0.f;
    } else {
        int ii = k - 128;
        v = (ii < in_c) ? root[ii * HID + o] : 0.f;
    }
    Wp[l * 5120 + kc * 128 + o * 4 + j] = v;
}

// ---------------- fused RGCN layer ----------------
// Quarter-wave = 1 node: q = (t>>4)&3 selects node, p = t&15 selects a DIM
// PAIR (dims 2p, 2p+1). Gathers are __half2 dwords -> one wave instruction
// advances 4 nodes (vs 2 in R6): gather count, address math, srcs loads and
// adds per edge-slot all halve. Batch of 8 slots: pk_add_f16 tree (<=8 values,
// dummy pads are exact zeros) spilled to fp32 per batch. Fold per run; phase-2
// layout identical to R6 (float2 stores into sAgg[16][160]).
static __global__ __launch_bounds__(256, 6) void k_layer(
    const __half2* __restrict__ tab, const int* __restrict__ offs,
    const int* __restrict__ cnt, const int* __restrict__ srcs,
    const float* __restrict__ comp, const float* __restrict__ Wp,
    const float* __restrict__ bias, __half* __restrict__ hout,
    float* __restrict__ hall, int hall_off) {
    __shared__ __align__(16) float sAgg[16][160];   // 10 KB
    int t = threadIdx.x;
    int wave = t >> 6, q = (t >> 4) & 3, p = t & 15;

    float4 cw0 = *(const float4*)(comp + 0);        // SGPR-resident
    float4 cw1 = *(const float4*)(comp + 4);
    float4 cw2 = *(const float4*)(comp + 8);
    float4 cw3 = *(const float4*)(comp + 12);
    float4 cw4 = *(const float4*)(comp + 16);

    int n = blockIdx.x * 16 + wave * 4 + q;         // N_NODES = 6250*16
    int s5 = n * N_REL;
    int oo[6], cc[5];
#pragma unroll
    for (int r = 0; r < 5; r++) { oo[r] = offs[s5 + r]; cc[r] = cnt[s5 + r]; }
    oo[5] = oo[4] + ((cc[4] + 7) & ~7);             // padded end

    __half2 selfh = tab[n * 16 + p];
    float a0x = 0.f, a0y = 0.f, a1x = 0.f, a1y = 0.f;
    float a2x = 0.f, a2y = 0.f, a3x = 0.f, a3y = 0.f;

#pragma unroll
    for (int r = 0; r < 5; r++) {
        int pR = oo[r], pr = oo[r + 1] - pR;
        const int* sp = srcs + pR;                  // 32B-aligned
        int4 e0 = *(const int4*)(sp);               // per-quad broadcast
        int4 e1 = *(const int4*)(sp + 4);
        __half2 g0 = tab[e0.x * 16 + p], g1 = tab[e0.y * 16 + p];
        __half2 g2 = tab[e0.z * 16 + p], g3 = tab[e0.w * 16 + p];
        __half2 g4 = tab[e1.x * 16 + p], g5 = tab[e1.y * 16 + p];
        __half2 g6 = tab[e1.z * 16 + p], g7 = tab[e1.w * 16 + p];
        __half2 sb = __hadd2(__hadd2(__hadd2(g0, g1), __hadd2(g2, g3)),
                             __hadd2(__hadd2(g4, g5), __hadd2(g6, g7)));
        float2 bf = __half22float2(sb);
        float Sx = bf.x, Sy = bf.y;
        for (int s8 = 8; s8 < pr; s8 += 8) {        // residual batches (~20%)
            int4 f0 = *(const int4*)(sp + s8);
            int4 f1 = *(const int4*)(sp + s8 + 4);
            __half2 h0 = tab[f0.x * 16 + p], h1 = tab[f0.y * 16 + p];
            __half2 h2 = tab[f0.z * 16 + p], h3 = tab[f0.w * 16 + p];
            __half2 h4 = tab[f1.x * 16 + p], h5 = tab[f1.y * 16 + p];
            __half2 h6 = tab[f1.z * 16 + p], h7 = tab[f1.w * 16 + p];
            __half2 rb = __hadd2(__hadd2(__hadd2(h0, h1), __hadd2(h2, h3)),
                                 __hadd2(__hadd2(h4, h5), __hadd2(h6, h7)));
            float2 rf = __half22float2(rb);
            Sx += rf.x; Sy += rf.y;
        }
        int cr = cc[r];
        float ic = (cr > 0) ? __builtin_amdgcn_rcpf((float)cr) : 0.f;
        float scx = Sx * ic, scy = Sy * ic;
        float4 cw = (r == 0) ? cw0 : (r == 1) ? cw1 : (r == 2) ? cw2
                  : (r == 3) ? cw3 : cw4;           // resolved at unroll
        a0x += cw.x * scx; a0y += cw.x * scy;
        a1x += cw.y * scx; a1y += cw.y * scy;
        a2x += cw.z * scx; a2y += cw.z * scy;
        a3x += cw.w * scx; a3y += cw.w * scy;
    }
    int nl = wave * 4 + q;
    float2* row = (float2*)&sAgg[nl][0];            // 80 float2 per row
    row[p]      = make_float2(a0x, a0y);
    row[16 + p] = make_float2(a1x, a1y);
    row[32 + p] = make_float2(a2x, a2y);
    row[48 + p] = make_float2(a3x, a3y);
    row[64 + p] = __half22float2(selfh);            // self feature
    __syncthreads();

    // phase 2: K=160 matvec, W float4 from global (L1-resident 20 KB)
    int half = (t >> 5) & 1, i = t & 31;
    int mynode = wave * 4 + half * 2;
    const float4* wv = (const float4*)Wp;
    const float4* aA = (const float4*)&sAgg[mynode][0];
    const float4* aB = (const float4*)&sAgg[mynode + 1][0];
    float acc0 = 0.f, acc1 = 0.f;
#pragma unroll 8
    for (int kc = 0; kc < 40; kc++) {
        float4 w4 = wv[kc * 32 + i];
        float4 a4 = aA[kc];
        float4 b4 = aB[kc];
        acc0 += a4.x * w4.x + a4.y * w4.y + a4.z * w4.z + a4.w * w4.w;
        acc1 += b4.x * w4.x + b4.y * w4.y + b4.z * w4.z + b4.w * w4.w;
    }
    float bi = bias[i];
    float v0 = tanhf(acc0 + bi);
    float v1 = tanhf(acc1 + bi);
    int n0 = blockIdx.x * 16 + mynode;
    hall[n0 * 128 + hall_off + i] = v0;             // fp32 for the MLP
    hall[(n0 + 1) * 128 + hall_off + i] = v1;
    hout[n0 * 32 + i] = __float2half(v0);           // fp16 gather table
    hout[(n0 + 1) * 32 + i] = __float2half(v1);
}

// ---------------- final MLP: 16 graphs/block ----------------
static __global__ __launch_bounds__(256) void k_mlp(
    const float* __restrict__ hall, const int* __restrict__ uidx,
    const int* __restrict__ iidx, const float* __restrict__ w1,
    const float* __restrict__ b1, const float* __restrict__ w2,
    const float* __restrict__ b2, float* __restrict__ out) {
    __shared__ float sg[4][4][256];                 // 16 KB
    int t = threadIdx.x, wave = t >> 6, lane = t & 63;
    int g0 = blockIdx.x * 16 + wave * 4;
#pragma unroll
    for (int gg = 0; gg < 4; gg++) {
        int g = g0 + gg;
        int u = uidx[g], it = iidx[g];
        sg[wave][gg][lane]       = hall[u * 128 + lane];
        sg[wave][gg][64 + lane]  = hall[u * 128 + 64 + lane];
        sg[wave][gg][128 + lane] = hall[it * 128 + lane];
        sg[wave][gg][192 + lane] = hall[it * 128 + 64 + lane];
    }
    __syncthreads();
    float a0[4], a1[4];
#pragma unroll
    for (int gg = 0; gg < 4; gg++) { a0[gg] = b1[lane]; a1[gg] = b1[64 + lane]; }
#pragma unroll 4
    for (int k = 0; k < 256; k++) {
        float wa = w1[k * 128 + lane];
        float wb = w1[k * 128 + 64 + lane];
#pragma unroll
        for (int gg = 0; gg < 4; gg++) {
            float gk = sg[wave][gg][k];
            a0[gg] += gk * wa; a1[gg] += gk * wb;
        }
    }
    float w2a = w2[lane], w2b = w2[64 + lane], bb = b2[0];
#pragma unroll
    for (int gg = 0; gg < 4; gg++) {
        float z0 = fmaxf(a0[gg], 0.f), z1 = fmaxf(a1[gg], 0.f);
        float part = z0 * w2a + z1 * w2b;
#pragma unroll
        for (int off = 32; off > 0; off >>= 1) part += __shfl_xor(part, off);
        if (lane == 0) out[g0 + gg] = part + bb;
    }
}

// ---------------- launcher ----------------
extern "C" void kernel_launch(void* const* d_in, const int* in_sizes, int n_in,
                              void* d_out, int out_size, void* d_ws, size_t ws_size,
                              hipStream_t stream) {
    const float* x  = (const float*)d_in[0];
    const int*   ei = (const int*)d_in[1];
    const int*   et = (const int*)d_in[2];
    const int*   ui = (const int*)d_in[3];
    const int*   ii = (const int*)d_in[4];
    const float* w1 = (const float*)d_in[21];
    const float* b1 = (const float*)d_in[22];
    const float* w2 = (const float*)d_in[23];
    const float* b2 = (const float*)d_in[24];

    // workspace layout (bytes, 128-aligned). ws_size >= 95,620,608 proven in R1.
    char* ws = (char*)d_ws;
    if (ws_size < 92167680UL) return;
    int*    gcur = (int*)(ws + 0);              // [196]
    int*    offs = (int*)(ws + 1024);           // [500000]
    int*    cnt  = (int*)(ws + 2001024);        // [500000]
    int*    srcs = (int*)(ws + 4001024);        // [196*30720] + 16 slack
    __half* ht0  = (__half*)(ws + 28085568);    // [100001*32] fp16
    __half* ht1  = (__half*)(ws + 34485632);    // [100001*32] fp16
    float*  Wp   = (float*)(ws + 40885760);     // [4*5120]
    float*  hall = (float*)(ws + 40967680);     // [100000*128] fp32
    unsigned long long* part = (unsigned long long*)hall;  // alias, 32.1 MB (dead later)

    hipMemsetAsync(gcur, 0, NBUCK * 4, stream);

    k_part<<<782, 256, 0, stream>>>(ei, et, gcur, part);
    k_bsort<<<NBUCK, 512, 0, stream>>>(part, gcur, offs, cnt, srcs);
    k_pad<<<12501, 256, 0, stream>>>(x, ht0, ht1, srcs);
    k_wprep4<<<dim3(20, 4), 256, 0, stream>>>(
        (const float*)d_in[5],  (const float*)d_in[7],
        (const float*)d_in[9],  (const float*)d_in[11],
        (const float*)d_in[13], (const float*)d_in[15],
        (const float*)d_in[17], (const float*)d_in[19], Wp);

    __half* tab[2] = {ht0, ht1};
    for (int l = 0; l < 4; l++) {
        const float* comp = (const float*)d_in[6 + 4 * l];
        const float* bias = (const float*)d_in[8 + 4 * l];
        k_layer<<<6250, 256, 0, stream>>>((const __half2*)tab[l & 1], offs, cnt,
                                          srcs, comp, Wp + l * 5120, bias,
                                          tab[(l + 1) & 1], hall, l * 32);
    }
    k_mlp<<<256, 256, 0, stream>>>(hall, ui, ii, w1, b1, w2, b2, (float*)d_out);
}

// Round 9
// 383.539 us; speedup vs baseline: 1.8860x; 1.2671x over previous
//
#include <hip/hip_runtime.h>
#include <hip/hip_bf16.h>
#include <hip/hip_fp16.h>

#define N_NODES 100000
#define N_EDGES 3200000
#define N_GRAPHS 4096
#define N_REL 5
#define N_BASES 4
#define HID 32
#define SEG (N_NODES*N_REL)
#define DUMMY N_NODES            // extra node whose fp16 feature row is all-zero

#define NBUCK 196                // buckets of 512 dst nodes
#define BCAP  20480              // part-record capacity per bucket
#define PBCAP 30720              // padded srcs capacity per bucket
#define NKEY  2560               // 512 nodes * 5 rels

typedef _Float16 half8 __attribute__((ext_vector_type(8)));
typedef float floatx4 __attribute__((ext_vector_type(4)));

// ---------------- CSR pass 1: partition edges into dst-range buckets ----------------
static __global__ __launch_bounds__(256) void k_part(const int* __restrict__ ei,
                                                     const int* __restrict__ et,
                                                     int* __restrict__ gcur,
                                                     unsigned long long* __restrict__ part) {
    __shared__ int hcnt[NBUCK];
    __shared__ int lbase[NBUCK];
    int t = threadIdx.x;
    if (t < NBUCK) hcnt[t] = 0;
    __syncthreads();
    int e0 = blockIdx.x * 4096;
    int src[16], bkt[16], lkey[16];
#pragma unroll
    for (int j = 0; j < 16; j++) {
        int e = e0 + j * 256 + t;
        if (e < N_EDGES) {
            int s = ei[e];
            int d = ei[N_EDGES + e];
            int r = et[e];
            src[j] = s; bkt[j] = d >> 9; lkey[j] = ((d & 511) * 5) + r;
            atomicAdd(&hcnt[bkt[j]], 1);
        } else bkt[j] = -1;
    }
    __syncthreads();
    if (t < NBUCK) lbase[t] = atomicAdd(&gcur[t], hcnt[t]);
    __syncthreads();
    if (t < NBUCK) hcnt[t] = 0;   // reuse as intra-block cursor
    __syncthreads();
#pragma unroll
    for (int j = 0; j < 16; j++) {
        if (bkt[j] >= 0) {
            int rank = atomicAdd(&hcnt[bkt[j]], 1);
            int p = lbase[bkt[j]] + rank;
            if (p < BCAP)
                part[(size_t)bkt[j] * BCAP + p] =
                    ((unsigned long long)(unsigned)lkey[j] << 32) | (unsigned)src[j];
        }
    }
}

// ---------------- CSR pass 2: per-bucket counting sort, runs PADDED to 8 ----------------
static __global__ __launch_bounds__(512) void k_bsort(const unsigned long long* __restrict__ part,
                                                      const int* __restrict__ gcur,
                                                      int* __restrict__ offs,
                                                      int* __restrict__ cnt,
                                                      int* __restrict__ srcs) {
    __shared__ int lhist[NKEY];      // 10 KB
    __shared__ int lscan[NKEY];      // 10 KB
    __shared__ int sscan[512];       // 2 KB
    __shared__ int lsrc[PBCAP];      // 120 KB
    int b = blockIdx.x;
    int t = threadIdx.x;
    int n = gcur[b]; if (n > BCAP) n = BCAP;
    const unsigned long long* reg = part + (size_t)b * BCAP;

#pragma unroll
    for (int k = t; k < NKEY; k += 512) lhist[k] = 0;
    __syncthreads();
    for (int i = t; i < n; i += 512)
        atomicAdd(&lhist[(int)(reg[i] >> 32)], 1);
    __syncthreads();

    // exclusive scan over PADDED counts (2560 = 512 threads x 5 keys)
    int loc[5]; int s5 = 0;
#pragma unroll
    for (int j = 0; j < 5; j++) { loc[j] = s5; s5 += (lhist[t * 5 + j] + 7) & ~7; }
    sscan[t] = s5;
    __syncthreads();
    for (int off = 1; off < 512; off <<= 1) {
        int x = (t >= off) ? sscan[t - off] : 0;
        __syncthreads();
        sscan[t] += x;
        __syncthreads();
    }
    int excl = sscan[t] - s5;
#pragma unroll
    for (int j = 0; j < 5; j++) lscan[t * 5 + j] = excl + loc[j];
    __syncthreads();
    int ptot = sscan[511]; if (ptot > PBCAP) ptot = PBCAP;

    int base = b * PBCAP;
#pragma unroll
    for (int j = 0; j < 5; j++) {
        int k = t * 5 + j;
        int segid = b * NKEY + k;
        if (segid < SEG) {
            cnt[segid]  = lhist[k];
            offs[segid] = base + lscan[k];
        }
    }
    __syncthreads();
    // reset cursors + dummy-fill padded region
#pragma unroll
    for (int k = t; k < NKEY; k += 512) lhist[k] = 0;
    for (int i = t; i < ptot; i += 512) lsrc[i] = DUMMY;
    __syncthreads();
    for (int i = t; i < n; i += 512) {
        unsigned long long u = reg[i];
        int k = (int)(u >> 32);
        int pos = lscan[k] + atomicAdd(&lhist[k], 1);
        if (pos < PBCAP) lsrc[pos] = (int)(u & 0xffffffffULL);
    }
    __syncthreads();
    for (int i = t; i < ptot; i += 512) srcs[base + i] = lsrc[i];
}

// ---------------- fp16 layer-0 table + dummy rows + srcs slack ----------------
static __global__ __launch_bounds__(256) void k_pad(const float* __restrict__ x,
                                                    __half* __restrict__ ht0,
                                                    __half* __restrict__ ht1,
                                                    int* __restrict__ srcs) {
    int tid = blockIdx.x * 256 + threadIdx.x;
    if (tid < (N_NODES + 1) * 32) {
        int nd = tid >> 5, ii = tid & 31;
        float v = (nd < N_NODES && ii < 4) ? x[(nd << 2) + ii] : 0.f;
        ht0[tid] = __float2half(v);
    } else {
        int r = tid - (N_NODES + 1) * 32;
        if (r < 32) ht1[N_NODES * 32 + r] = __float2half(0.f);   // ht1 dummy row
        else if (r < 48) srcs[NBUCK * PBCAP + (r - 32)] = DUMMY; // srcs slack
    }
}

// ---------------- weight prep: fp16 MFMA B-fragments, all 4 layers ----------------
// Per-layer block = 5*2*512 = 5120 halves. idx = ((l*5 + s)*2 + tile)*512 +
// lane*8 + j holds W_l[k = s*32 + (lane>>4)*8 + j][o = tile*16 + (lane&15)]
// (zero-padded rows). Grid must be exactly 20480 threads (80 blocks).
static __global__ __launch_bounds__(256) void k_wprepB(
    const float* __restrict__ ba0, const float* __restrict__ ro0,
    const float* __restrict__ ba1, const float* __restrict__ ro1,
    const float* __restrict__ ba2, const float* __restrict__ ro2,
    const float* __restrict__ ba3, const float* __restrict__ ro3,
    __half* __restrict__ Wb) {
    int idx = blockIdx.x * 256 + threadIdx.x;   // < 20480
    int j    = idx & 7;
    int lane = (idx >> 3) & 63;
    int tile = (idx >> 9) & 1;
    int ls   = idx >> 10;                       // l*5 + s, < 20
    int l    = ls / 5;
    int s    = ls - l * 5;
    const float* basis = (l == 0) ? ba0 : (l == 1) ? ba1 : (l == 2) ? ba2 : ba3;
    const float* root  = (l == 0) ? ro0 : (l == 1) ? ro1 : (l == 2) ? ro2 : ro3;
    int in_c = (l == 0) ? 4 : HID;
    int k = s * 32 + ((lane >> 4) << 3) + j;
    int o = tile * 16 + (lane & 15);
    float v;
    if (k < 128) {
        int b = k >> 5, ii = k & 31;
        v = (ii < in_c) ? basis[(b * in_c + ii) * HID + o] : 0.f;
    } else {
        int ii = k - 128;
        v = (ii < in_c) ? root[ii * HID + o] : 0.f;
    }
    Wb[idx] = __float2half(v);
}

// ---------------- fused RGCN layer ----------------
// Phase 1 (R7 structure): quarter-wave = 1 node, p = dim pair, __half2 dword
// gathers, 8-padded runs, per-run comp-fold. Deposits the K=160 aggregate
// vector as fp16 into sAgg16[16][168] (row = node, k contiguous; +8 halves
// row pad).
// Phase 2: [16x160]x[160x32] via 5x mfma_f32_16x16x32_f16 per 16-col tile;
// wave 0 -> cols 0-15, wave 1 -> cols 16-31. A: m=lane&15 (node),
// k=(lane>>4)*8+j. B: precomputed fragment (k_wprepB). C/D: col=lane&15,
// row=(lane>>4)*4+reg. Epilogue: bias+tanh, coalesced stores.
static __global__ __launch_bounds__(256, 6) void k_layer(
    const __half2* __restrict__ tab, const int* __restrict__ offs,
    const int* __restrict__ cnt, const int* __restrict__ srcs,
    const float* __restrict__ comp, const __half* __restrict__ Wbl,
    const float* __restrict__ bias, __half* __restrict__ hout,
    float* __restrict__ hall, int hall_off) {
    __shared__ __align__(16) __half sAgg16[16 * 168];   // 5.25 KB
    int t = threadIdx.x;
    int wave = t >> 6, q = (t >> 4) & 3, p = t & 15;

    float4 cw0 = *(const float4*)(comp + 0);        // SGPR-resident
    float4 cw1 = *(const float4*)(comp + 4);
    float4 cw2 = *(const float4*)(comp + 8);
    float4 cw3 = *(const float4*)(comp + 12);
    float4 cw4 = *(const float4*)(comp + 16);

    int n = blockIdx.x * 16 + wave * 4 + q;         // N_NODES = 6250*16
    int s5 = n * N_REL;
    int oo[6], cc[5];
#pragma unroll
    for (int r = 0; r < 5; r++) { oo[r] = offs[s5 + r]; cc[r] = cnt[s5 + r]; }
    oo[5] = oo[4] + ((cc[4] + 7) & ~7);             // padded end

    __half2 selfh = tab[n * 16 + p];
    float a0x = 0.f, a0y = 0.f, a1x = 0.f, a1y = 0.f;
    float a2x = 0.f, a2y = 0.f, a3x = 0.f, a3y = 0.f;

#pragma unroll
    for (int r = 0; r < 5; r++) {
        int pR = oo[r], pr = oo[r + 1] - pR;
        const int* sp = srcs + pR;                  // 32B-aligned
        int4 e0 = *(const int4*)(sp);               // per-quad broadcast
        int4 e1 = *(const int4*)(sp + 4);
        __half2 g0 = tab[e0.x * 16 + p], g1 = tab[e0.y * 16 + p];
        __half2 g2 = tab[e0.z * 16 + p], g3 = tab[e0.w * 16 + p];
        __half2 g4 = tab[e1.x * 16 + p], g5 = tab[e1.y * 16 + p];
        __half2 g6 = tab[e1.z * 16 + p], g7 = tab[e1.w * 16 + p];
        __half2 sb = __hadd2(__hadd2(__hadd2(g0, g1), __hadd2(g2, g3)),
                             __hadd2(__hadd2(g4, g5), __hadd2(g6, g7)));
        float2 bf = __half22float2(sb);
        float Sx = bf.x, Sy = bf.y;
        for (int s8 = 8; s8 < pr; s8 += 8) {        // residual batches (~20%)
            int4 f0 = *(const int4*)(sp + s8);
            int4 f1 = *(const int4*)(sp + s8 + 4);
            __half2 h0 = tab[f0.x * 16 + p], h1 = tab[f0.y * 16 + p];
            __half2 h2 = tab[f0.z * 16 + p], h3 = tab[f0.w * 16 + p];
            __half2 h4 = tab[f1.x * 16 + p], h5 = tab[f1.y * 16 + p];
            __half2 h6 = tab[f1.z * 16 + p], h7 = tab[f1.w * 16 + p];
            __half2 rb = __hadd2(__hadd2(__hadd2(h0, h1), __hadd2(h2, h3)),
                                 __hadd2(__hadd2(h4, h5), __hadd2(h6, h7)));
            float2 rf = __half22float2(rb);
            Sx += rf.x; Sy += rf.y;
        }
        int cr = cc[r];
        float ic = (cr > 0) ? __builtin_amdgcn_rcpf((float)cr) : 0.f;
        float scx = Sx * ic, scy = Sy * ic;
        float4 cw = (r == 0) ? cw0 : (r == 1) ? cw1 : (r == 2) ? cw2
                  : (r == 3) ? cw3 : cw4;           // resolved at unroll
        a0x += cw.x * scx; a0y += cw.x * scy;
        a1x += cw.y * scx; a1y += cw.y * scy;
        a2x += cw.z * scx; a2y += cw.z * scy;
        a3x += cw.w * scx; a3y += cw.w * scy;
    }
    int nl = wave * 4 + q;
    __half2* row = (__half2*)(sAgg16 + nl * 168);   // k/2 index
    row[p]      = __float22half2_rn(make_float2(a0x, a0y));   // k = 0..31
    row[16 + p] = __float22half2_rn(make_float2(a1x, a1y));   // k = 32..63
    row[32 + p] = __float22half2_rn(make_float2(a2x, a2y));   // k = 64..95
    row[48 + p] = __float22half2_rn(make_float2(a3x, a3y));   // k = 96..127
    row[64 + p] = selfh;                                      // k = 128..159
    __syncthreads();

    // phase 2: [16x160] x [160x32] via 5x mfma_f32_16x16x32_f16 per tile
    if (wave < 2) {
        int lane = t & 63;
        floatx4 acc = {0.f, 0.f, 0.f, 0.f};
        const __half* aBase = sAgg16 + (lane & 15) * 168 + ((lane >> 4) << 3);
        const __half* bBase = Wbl + wave * 512 + lane * 8;
#pragma unroll
        for (int s = 0; s < 5; s++) {
            half8 a = *(const half8*)(aBase + s * 32);
            half8 b = *(const half8*)(bBase + s * 1024);
            acc = __builtin_amdgcn_mfma_f32_16x16x32_f16(a, b, acc, 0, 0, 0);
        }
        int o = wave * 16 + (lane & 15);
        float bi = bias[o];
#pragma unroll
        for (int r = 0; r < 4; r++) {
            int node = blockIdx.x * 16 + ((lane >> 4) << 2) + r;
            float v = tanhf(acc[r] + bi);
            hall[node * 128 + hall_off + o] = v;    // fp32 for the MLP
            hout[node * 32 + o] = __float2half(v);  // fp16 gather table
        }
    }
}

// ---------------- final MLP: 16 graphs/block ----------------
static __global__ __launch_bounds__(256) void k_mlp(
    const float* __restrict__ hall, const int* __restrict__ uidx,
    const int* __restrict__ iidx, const float* __restrict__ w1,
    const float* __restrict__ b1, const float* __restrict__ w2,
    const float* __restrict__ b2, float* __restrict__ out) {
    __shared__ float sg[4][4][256];                 // 16 KB
    int t = threadIdx.x, wave = t >> 6, lane = t & 63;
    int g0 = blockIdx.x * 16 + wave * 4;
#pragma unroll
    for (int gg = 0; gg < 4; gg++) {
        int g = g0 + gg;
        int u = uidx[g], it = iidx[g];
        sg[wave][gg][lane]       = hall[u * 128 + lane];
        sg[wave][gg][64 + lane]  = hall[u * 128 + 64 + lane];
        sg[wave][gg][128 + lane] = hall[it * 128 + lane];
        sg[wave][gg][192 + lane] = hall[it * 128 + 64 + lane];
    }
    __syncthreads();
    float a0[4], a1[4];
#pragma unroll
    for (int gg = 0; gg < 4; gg++) { a0[gg] = b1[lane]; a1[gg] = b1[64 + lane]; }
#pragma unroll 4
    for (int k = 0; k < 256; k++) {
        float wa = w1[k * 128 + lane];
        float wb = w1[k * 128 + 64 + lane];
#pragma unroll
        for (int gg = 0; gg < 4; gg++) {
            float gk = sg[wave][gg][k];
            a0[gg] += gk * wa; a1[gg] += gk * wb;
        }
    }
    float w2a = w2[lane], w2b = w2[64 + lane], bb = b2[0];
#pragma unroll
    for (int gg = 0; gg < 4; gg++) {
        float z0 = fmaxf(a0[gg], 0.f), z1 = fmaxf(a1[gg], 0.f);
        float part = z0 * w2a + z1 * w2b;
#pragma unroll
        for (int off = 32; off > 0; off >>= 1) part += __shfl_xor(part, off);
        if (lane == 0) out[g0 + gg] = part + bb;
    }
}

// ---------------- launcher ----------------
extern "C" void kernel_launch(void* const* d_in, const int* in_sizes, int n_in,
                              void* d_out, int out_size, void* d_ws, size_t ws_size,
                              hipStream_t stream) {
    const float* x  = (const float*)d_in[0];
    const int*   ei = (const int*)d_in[1];
    const int*   et = (const int*)d_in[2];
    const int*   ui = (const int*)d_in[3];
    const int*   ii = (const int*)d_in[4];
    const float* w1 = (const float*)d_in[21];
    const float* b1 = (const float*)d_in[22];
    const float* w2 = (const float*)d_in[23];
    const float* b2 = (const float*)d_in[24];

    // workspace layout (bytes, 128-aligned). ws_size >= 95,620,608 proven in R1.
    char* ws = (char*)d_ws;
    if (ws_size < 92167680UL) return;
    int*    gcur = (int*)(ws + 0);              // [196]
    int*    offs = (int*)(ws + 1024);           // [500000]
    int*    cnt  = (int*)(ws + 2001024);        // [500000]
    int*    srcs = (int*)(ws + 4001024);        // [196*30720] + 16 slack
    __half* ht0  = (__half*)(ws + 28085568);    // [100001*32] fp16
    __half* ht1  = (__half*)(ws + 34485632);    // [100001*32] fp16
    __half* Wb   = (__half*)(ws + 40885760);    // [20480] fp16 B-fragments
    float*  hall = (float*)(ws + 40967680);     // [100000*128] fp32
    unsigned long long* part = (unsigned long long*)hall;  // alias (dead later)

    hipMemsetAsync(gcur, 0, NBUCK * 4, stream);

    k_part<<<782, 256, 0, stream>>>(ei, et, gcur, part);
    k_bsort<<<NBUCK, 512, 0, stream>>>(part, gcur, offs, cnt, srcs);
    k_pad<<<12501, 256, 0, stream>>>(x, ht0, ht1, srcs);
    k_wprepB<<<80, 256, 0, stream>>>(           // 80*256 = 20480 = 4 layers * 5120
        (const float*)d_in[5],  (const float*)d_in[7],
        (const float*)d_in[9],  (const float*)d_in[11],
        (const float*)d_in[13], (const float*)d_in[15],
        (const float*)d_in[17], (const float*)d_in[19], Wb);

    __half* tab[2] = {ht0, ht1};
    for (int l = 0; l < 4; l++) {
        const float* comp = (const float*)d_in[6 + 4 * l];
        const float* bias = (const float*)d_in[8 + 4 * l];
        k_layer<<<6250, 256, 0, stream>>>((const __half2*)tab[l & 1], offs, cnt,
                                          srcs, comp, Wb + l * 5120, bias,
                                          tab[(l + 1) & 1], hall, l * 32);
    }
    k_mlp<<<256, 256, 0, stream>>>(hall, ui, ii, w1, b1, w2, b2, (float*)d_out);
}